// Round 8
// baseline (96.314 us; speedup 1.0000x reference)
//
#include <hip/hip_runtime.h>

typedef __attribute__((ext_vector_type(8))) short short8;
typedef __attribute__((ext_vector_type(4))) float f32x4;

// round-to-nearest-even f32 -> bf16 bits
__device__ __forceinline__ unsigned short f2b(float f) {
  unsigned int u = __float_as_uint(f);
  return (unsigned short)((u + 0x7FFFu + ((u >> 16) & 1u)) >> 16);
}
__device__ __forceinline__ unsigned pk2(float a, float b) {
  return (unsigned)f2b(a) | ((unsigned)f2b(b) << 16);
}

// d_out is float*, holding Re(out) only:
// Re(out)[b, i*64+k] = sum_j cos(phase[j][i])*hr[b,j*64+k] - sin(phase[j][i])*hi[b,j*64+k]
//
// BARRIER-FREE wave-autonomous design: 256 threads = 4 waves; wave w owns
// batch b = blockIdx.x*4 + w entirely (all 64 i, all 64 k). Each wave stages
// its own H re/im into a private 8KB LDS region (bf16, [k][j] rows, XOR-
// swizzled) and consumes it — same-wave DS ops are processed in-order by the
// LDS pipe, so NO __syncthreads anywhere. k is processed in 2 halves of 32.
// psi A-fragments (4 m-tiles x 2 j-chunks x {cos,-sin}) built in-register.
__global__ __launch_bounds__(256, 3) void tnn_kernel(
    const float* __restrict__ phase,
    const float* __restrict__ hr, const float* __restrict__ hi,
    float* __restrict__ out) {
  __shared__ alignas(16) char lds[32768];
  const int tid = threadIdx.x;
  const int lane = tid & 63;
  const int w = tid >> 6;
  const int b = blockIdx.x * 4 + w;
  char* ldsw = lds + w * 8192;      // [plane 2][row 32][128B], planes at +0/+4096

  const int jo = lane & 7;          // j-octet (8 octets cover j=0..63)
  const int kq = lane >> 3;         // k-quad within the 32-k half

  const float* hre = hr + (size_t)b * 4096;
  const float* him = hi + (size_t)b * 4096;

  // ---- psi A-fragments: Are = cos(phase[j][i]), Ans = -sin, all 4 i-tiles ----
  // A-frag (16x16x32): row m = lane&15, c-chunk = (lane>>4)*8 + q.
  short8 Are[4][2], Ans[4][2];
#pragma unroll
  for (int it = 0; it < 4; ++it) {
#pragma unroll
    for (int ks = 0; ks < 2; ++ks) {
      const int i = it * 16 + (lane & 15);
      const int j0 = ks * 32 + (lane >> 4) * 8;
#pragma unroll
      for (int q = 0; q < 8; ++q) {
        float p = phase[(j0 + q) * 64 + i];
        float s, c;
        __sincosf(p, &s, &c);
        Are[it][ks][q] = (short)f2b(c);
        Ans[it][ks][q] = (short)f2b(-s);
      }
    }
  }

#pragma unroll
  for (int kh = 0; kh < 2; ++kh) {
    // ---- stage this k-half: float4 loads + register 8jx4k transpose ----
    f32x4 vr[8], vi[8];
    const f32x4* sr = reinterpret_cast<const f32x4*>(hre + kh * 32 + kq * 4);
    const f32x4* si = reinterpret_cast<const f32x4*>(him + kh * 32 + kq * 4);
#pragma unroll
    for (int q = 0; q < 8; ++q) vr[q] = sr[(jo * 8 + q) * 16];
#pragma unroll
    for (int q = 0; q < 8; ++q) vi[q] = si[(jo * 8 + q) * 16];
#pragma unroll
    for (int kk = 0; kk < 4; ++kk) {
      const int row = kq * 4 + kk;
      const int swz = (jo * 16) ^ ((row & 7) << 4);
      uint4 wvr, wvi;
      wvr.x = pk2(vr[0][kk], vr[1][kk]);
      wvr.y = pk2(vr[2][kk], vr[3][kk]);
      wvr.z = pk2(vr[4][kk], vr[5][kk]);
      wvr.w = pk2(vr[6][kk], vr[7][kk]);
      wvi.x = pk2(vi[0][kk], vi[1][kk]);
      wvi.y = pk2(vi[2][kk], vi[3][kk]);
      wvi.z = pk2(vi[4][kk], vi[5][kk]);
      wvi.w = pk2(vi[6][kk], vi[7][kk]);
      *reinterpret_cast<uint4*>(ldsw + row * 128 + swz) = wvr;
      *reinterpret_cast<uint4*>(ldsw + 4096 + row * 128 + swz) = wvi;
    }
    // same-wave DS pipe is in-order; just stop the compiler reordering
    asm volatile("" ::: "memory");

    // ---- compute 2 n-tiles of this half ----
#pragma unroll
    for (int nt = 0; nt < 2; ++nt) {
      const int rrow = nt * 16 + (lane & 15);
      uint4 xr4[2], xi4[2];
#pragma unroll
      for (int ks = 0; ks < 2; ++ks) {
        const int byte = rrow * 128 + ((ks * 64 + (lane >> 4) * 16) ^ ((rrow & 7) << 4));
        xr4[ks] = *reinterpret_cast<const uint4*>(ldsw + byte);
        xi4[ks] = *reinterpret_cast<const uint4*>(ldsw + 4096 + byte);
      }
      f32x4 acc[4] = {};
#pragma unroll
      for (int mt = 0; mt < 4; ++mt) {
#pragma unroll
        for (int ks = 0; ks < 2; ++ks) {
          short8 xr = __builtin_bit_cast(short8, xr4[ks]);
          short8 xi = __builtin_bit_cast(short8, xi4[ks]);
          acc[mt] = __builtin_amdgcn_mfma_f32_16x16x32_bf16(Are[mt][ks], xr, acc[mt], 0, 0, 0);
          acc[mt] = __builtin_amdgcn_mfma_f32_16x16x32_bf16(Ans[mt][ks], xi, acc[mt], 0, 0, 0);
        }
      }
      // ---- store: C/D (16x16x32): col = lane&15, row = (lane>>4)*4 + r ----
      const int kc = kh * 32 + nt * 16 + (lane & 15);
      const size_t obase = (size_t)b * 4096;
#pragma unroll
      for (int mt = 0; mt < 4; ++mt) {
#pragma unroll
        for (int r = 0; r < 4; ++r) {
          const int i = mt * 16 + (lane >> 4) * 4 + r;
          out[obase + (size_t)i * 64 + kc] = acc[mt][r];
        }
      }
    }
    // next half's ds_writes must not be compiler-hoisted above this half's reads
    asm volatile("" ::: "memory");
  }
}

extern "C" void kernel_launch(void* const* d_in, const int* in_sizes, int n_in,
                              void* d_out, int out_size, void* d_ws, size_t ws_size,
                              hipStream_t stream) {
  const float* phase = (const float*)d_in[0];
  const float* hr = (const float*)d_in[1];
  const float* hi = (const float*)d_in[2];
  float* out = (float*)d_out;

  tnn_kernel<<<2048, 256, 0, stream>>>(phase, hr, hi, out);
}

// Round 9
// 66.753 us; speedup vs baseline: 1.4428x; 1.4428x over previous
//
#include <hip/hip_runtime.h>

typedef __attribute__((ext_vector_type(8))) short short8;
typedef __attribute__((ext_vector_type(4))) float f32x4;

// round-to-nearest-even f32 -> bf16 bits
__device__ __forceinline__ unsigned short f2b(float f) {
  unsigned int u = __float_as_uint(f);
  return (unsigned short)((u + 0x7FFFu + ((u >> 16) & 1u)) >> 16);
}
__device__ __forceinline__ unsigned pk2(float a, float b) {
  return (unsigned)f2b(a) | ((unsigned)f2b(b) << 16);
}

// d_out is float*, holding Re(out) only:
// Re(out)[b, i*64+k] = sum_j cos(phase[j][i])*hr[b,j*64+k] - sin(phase[j][i])*hi[b,j*64+k]
//
// R6 structure (best known: 76.6us): 512 thr = 8 waves, 2 batches, 32KB LDS,
// float4 staging loads + register 8jx4k transpose into XOR-swizzled [k][j]
// bf16 tiles; psi (cos,-sin) fragments in-register per wave.
// R8 change (single variable): output stores are NONTEMPORAL - the 128MB
// output stream should stop evicting input lines from L2/L3, raising the
// input read hit rate (FETCH_SIZE is the diagnostic).
__global__ __launch_bounds__(512, 4) void tnn_kernel(
    const float* __restrict__ phase,
    const float* __restrict__ hr, const float* __restrict__ hi,
    float* __restrict__ out) {
  __shared__ alignas(16) char lds[32768];
  const int tid = threadIdx.x;
  const int lane = tid & 63;
  const int w8 = tid >> 6;
  const int b0 = blockIdx.x * 2;

  const int bb = w8 >> 2;           // batch this wave computes
  const int ibase = (w8 & 3) * 16;  // i-quarter (M=16)

  // ---- stage X into LDS: float4 loads + in-register 8jx4k transpose ----
  {
    const int p = w8 & 3;           // plane: (batch<<1)|comp
    const int jh = w8 >> 2;         // j-half
    const int jo = lane & 3;        // j-octet within half
    const int kq = lane >> 2;       // k-quad
    const float* src = (p & 1 ? hi : hr) + (size_t)(b0 + (p >> 1)) * 4096;
    const int j0 = jh * 32 + jo * 8;
    const f32x4* sp = reinterpret_cast<const f32x4*>(src + (size_t)j0 * 64 + kq * 4);
    f32x4 v[8];
#pragma unroll
    for (int q = 0; q < 8; ++q) v[q] = sp[q * 16];  // next j-row = 64 floats = 16 float4
    char* plane = lds + p * 8192;
    const int colb = jh * 64 + jo * 16;             // byte col = 2*j0
#pragma unroll
    for (int kk = 0; kk < 4; ++kk) {
      const int row = kq * 4 + kk;                  // k
      uint4 wv;
      wv.x = pk2(v[0][kk], v[1][kk]);
      wv.y = pk2(v[2][kk], v[3][kk]);
      wv.z = pk2(v[4][kk], v[5][kk]);
      wv.w = pk2(v[6][kk], v[7][kk]);
      *reinterpret_cast<uint4*>(plane + row * 128 + (colb ^ ((row & 7) << 4))) = wv;
    }
  }

  // ---- psi A-fragments in-register: Are = cos(phase[j][i]), Ans = -sin ----
  // A-frag (16x16x32): row m = lane&15, k = (lane>>4)*8 + q.
  short8 Are[2], Ans[2];
#pragma unroll
  for (int ks = 0; ks < 2; ++ks) {
    const int i = ibase + (lane & 15);
    const int j0 = ks * 32 + (lane >> 4) * 8;
#pragma unroll
    for (int q = 0; q < 8; ++q) {
      float pph = phase[(j0 + q) * 64 + i];
      float s, c;
      __sincosf(pph, &s, &c);
      Are[ks][q] = (short)f2b(c);
      Ans[ks][q] = (short)f2b(-s);
    }
  }

  __syncthreads();

  // ---- MFMA compute (real part only) ----
  f32x4 acc[4] = {};
  const char* Xre = lds + (bb * 2 + 0) * 8192;
  const char* Xim = lds + (bb * 2 + 1) * 8192;

#pragma unroll
  for (int kt = 0; kt < 4; ++kt) {
    const int row = kt * 16 + (lane & 15);
#pragma unroll
    for (int ks = 0; ks < 2; ++ks) {
      const int cbyte = ks * 64 + (lane >> 4) * 16;
      const int byte = row * 128 + (cbyte ^ ((row & 7) << 4));
      uint4 xr4 = *reinterpret_cast<const uint4*>(Xre + byte);
      uint4 xi4 = *reinterpret_cast<const uint4*>(Xim + byte);
      short8 xr = __builtin_bit_cast(short8, xr4);
      short8 xi = __builtin_bit_cast(short8, xi4);
      acc[kt] = __builtin_amdgcn_mfma_f32_16x16x32_bf16(Are[ks], xr, acc[kt], 0, 0, 0);
      acc[kt] = __builtin_amdgcn_mfma_f32_16x16x32_bf16(Ans[ks], xi, acc[kt], 0, 0, 0);
    }
  }

  // ---- epilogue: nontemporal scalar f32 stores (real part) ----
  // C/D (16x16x32): col = lane&15, row = (lane>>4)*4 + r.
  const size_t obase = (size_t)(b0 + bb) * 4096;
#pragma unroll
  for (int kt = 0; kt < 4; ++kt) {
#pragma unroll
    for (int r = 0; r < 4; ++r) {
      int i = ibase + (lane >> 4) * 4 + r;
      int kc = kt * 16 + (lane & 15);
      __builtin_nontemporal_store(acc[kt][r], &out[obase + (size_t)i * 64 + kc]);
    }
  }
}

extern "C" void kernel_launch(void* const* d_in, const int* in_sizes, int n_in,
                              void* d_out, int out_size, void* d_ws, size_t ws_size,
                              hipStream_t stream) {
  const float* phase = (const float*)d_in[0];
  const float* hr = (const float*)d_in[1];
  const float* hi = (const float*)d_in[2];
  float* out = (float*)d_out;

  tnn_kernel<<<4096, 512, 0, stream>>>(phase, hr, hi, out);
}